// Round 1
// baseline (317.958 us; speedup 1.0000x reference)
//
#include <hip/hip_runtime.h>

namespace {

constexpr int kB = 8, kO = 128, kI = 128, kD = 1024;
constexpr long kOutAttnOff = (long)kB * kO * kD;   // 1,048,576 floats

__device__ __forceinline__ float leaky(float x) { return x > 0.0f ? x : 0.01f * x; }

// ---------------------------------------------------------------------------
// Generic fp32 tiled GEMM: C = op(A @ W (+bias)), 64x64 tile, BK=16,
// 256 threads, 4x4 micro-tile. A is [M,K] row-major (dual-source along K:
// k < ksplit reads A1, else A2 at k-ksplit; both share lda). W is [K,N]
// row-major. Optional batch strides sA/sW/sC selected by blockIdx.z.
// M,N multiples of 64; K multiple of 16 (all true for this problem).
// ---------------------------------------------------------------------------
template<bool BIAS, bool LEAKYOUT>
__global__ __launch_bounds__(256)
void gemm64(const float* __restrict__ A1, const float* __restrict__ A2, int ksplit,
            int lda, const float* __restrict__ W, int ldw,
            const float* __restrict__ bias, float* __restrict__ C, int ldc,
            int K, long sA, long sW, long sC)
{
    __shared__ float As[16][68];   // [k][m], padded: store-conflict ~2-way
    __shared__ float Ws[16][68];   // [k][n]
    const int tid = threadIdx.x;
    const int bn = blockIdx.x * 64;
    const int bm = blockIdx.y * 64;
    const long z = blockIdx.z;

    const int tx = tid & 15;        // n group: cols tx*4..+3
    const int ty = tid >> 4;        // m group: rows ty*4..+3
    const int ar = tid >> 2;        // A-load row 0..63
    const int ac = (tid & 3) << 2;  // A-load k 0,4,8,12
    const int wr = tid >> 4;        // W-load row 0..15
    const int wc = (tid & 15) << 2; // W-load col 0..60

    const float* Az1 = A1 + z * sA;
    const float* Az2 = A2 + z * sA;
    const float* Wz  = W  + z * sW;
    float*       Cz  = C  + z * sC;

    float acc[4][4];
#pragma unroll
    for (int i = 0; i < 4; ++i)
#pragma unroll
        for (int j = 0; j < 4; ++j) acc[i][j] = 0.0f;

    for (int k0 = 0; k0 < K; k0 += 16) {
        const float* Asrc;
        int kc;
        if (k0 < ksplit) { Asrc = Az1; kc = k0; }
        else             { Asrc = Az2; kc = k0 - ksplit; }
        const float4 a0 = *(const float4*)&Asrc[(long)(bm + ar) * lda + kc + ac];
        const float4 w0 = *(const float4*)&Wz[(long)(k0 + wr) * ldw + bn + wc];
        __syncthreads();
        As[ac + 0][ar] = a0.x;
        As[ac + 1][ar] = a0.y;
        As[ac + 2][ar] = a0.z;
        As[ac + 3][ar] = a0.w;
        *(float4*)&Ws[wr][wc] = w0;
        __syncthreads();
#pragma unroll
        for (int kk = 0; kk < 16; ++kk) {
            const float4 av = *(const float4*)&As[kk][ty * 4];  // 4 addrs, bcast
            const float4 bv = *(const float4*)&Ws[kk][tx * 4];  // 2-way, free
            const float a[4] = {av.x, av.y, av.z, av.w};
            const float b[4] = {bv.x, bv.y, bv.z, bv.w};
#pragma unroll
            for (int i = 0; i < 4; ++i)
#pragma unroll
                for (int j = 0; j < 4; ++j)
                    acc[i][j] = fmaf(a[i], b[j], acc[i][j]);
        }
    }

#pragma unroll
    for (int i = 0; i < 4; ++i) {
        const int m = bm + ty * 4 + i;
        float4 v = make_float4(acc[i][0], acc[i][1], acc[i][2], acc[i][3]);
        if (BIAS) {
            const float4 bb = *(const float4*)&bias[bn + tx * 4];
            v.x += bb.x; v.y += bb.y; v.z += bb.z; v.w += bb.w;
        }
        if (LEAKYOUT) {
            v.x = leaky(v.x); v.y = leaky(v.y); v.z = leaky(v.z); v.w = leaky(v.w);
        }
        *(float4*)&Cz[(long)m * ldc + bn + tx * 4] = v;
    }
}

// ---------------------------------------------------------------------------
// Fused score + mask + softmax.
// Block: b = blockIdx.x, o-tile of 4 = blockIdx.y. 256 threads = 4 waves,
// one wave per o-row (wave-local softmax => no cross-wave reduction).
// Thread owns i = lane and i+64. score_w and the 4 s_out rows are staged in
// LDS once; s_ctx is staged in 128x64 chunks reused by all 4 waves.
// ---------------------------------------------------------------------------
__global__ __launch_bounds__(256)
void score_softmax(const float* __restrict__ s_out, const float* __restrict__ s_ctx,
                   const float* __restrict__ score_w, const float* __restrict__ score_b,
                   const int* __restrict__ mask, float* __restrict__ attn)
{
    __shared__ float As[4][1028];   // 4 o-rows, padded for b128 alignment
    __shared__ float Cs[128][68];   // s_ctx chunk [i][k], pad 4 -> conflict-free b128
    __shared__ float Wsh[1024];
    __shared__ int   Msk[128];

    const int b   = blockIdx.x;
    const int o0  = blockIdx.y * 4;
    const int tid = threadIdx.x;
    const int wv  = tid >> 6;   // 0..3 : o index (uniform per wave)
    const int ln  = tid & 63;   // i low half

    const float* arow = s_out + (long)(b * kO + o0) * kD;
#pragma unroll
    for (int q = 0; q < 4; ++q) {           // 1024 float4 total
        const int t  = tid + q * 256;
        const int r  = t >> 8;              // 256 float4 per row
        const int c4 = (t & 255) * 4;
        const float4 v = *(const float4*)&arow[(long)r * kD + c4];
        *(float4*)&As[r][c4] = v;
    }
    {
        const float4 v = *(const float4*)&score_w[tid * 4];
        *(float4*)&Wsh[tid * 4] = v;
    }
    if (tid < 128) Msk[tid] = mask[b * kI + tid];

    float acc0 = 0.0f, acc1 = 0.0f;
    const float* crow = s_ctx + (long)b * kI * kD;

    for (int dc = 0; dc < kD; dc += 64) {
        __syncthreads();                    // protect Cs from previous chunk
#pragma unroll
        for (int q = 0; q < 8; ++q) {       // 128x64 floats = 2048 float4
            const int t  = tid + q * 256;
            const int r  = t >> 4;          // 0..127
            const int c4 = (t & 15) * 4;    // 0..60
            const float4 v = *(const float4*)&crow[(long)r * kD + dc + c4];
            *(float4*)&Cs[r][c4] = v;
        }
        __syncthreads();
#pragma unroll
        for (int kk = 0; kk < 64; kk += 4) {
            const float4 w4 = *(const float4*)&Wsh[dc + kk];
            const float4 av = *(const float4*)&As[wv][dc + kk];   // wave-uniform
            const float4 c0 = *(const float4*)&Cs[ln][kk];
            const float4 c1 = *(const float4*)&Cs[ln + 64][kk];
            acc0 = fmaf(leaky(av.x + c0.x), w4.x, acc0);
            acc0 = fmaf(leaky(av.y + c0.y), w4.y, acc0);
            acc0 = fmaf(leaky(av.z + c0.z), w4.z, acc0);
            acc0 = fmaf(leaky(av.w + c0.w), w4.w, acc0);
            acc1 = fmaf(leaky(av.x + c1.x), w4.x, acc1);
            acc1 = fmaf(leaky(av.y + c1.y), w4.y, acc1);
            acc1 = fmaf(leaky(av.z + c1.z), w4.z, acc1);
            acc1 = fmaf(leaky(av.w + c1.w), w4.w, acc1);
        }
    }

    const float negInf = -__builtin_huge_valf();
    const float sb = score_b[0];
    float s0 = acc0 + sb;
    float s1 = acc1 + sb;
    if (Msk[ln]      != 0) s0 = negInf;
    if (Msk[ln + 64] != 0) s1 = negInf;

    float m = fmaxf(s0, s1);
#pragma unroll
    for (int d = 1; d < 64; d <<= 1) m = fmaxf(m, __shfl_xor(m, d, 64));
    const float e0 = __expf(s0 - m);
    const float e1 = __expf(s1 - m);
    float sum = e0 + e1;
#pragma unroll
    for (int d = 1; d < 64; d <<= 1) sum += __shfl_xor(sum, d, 64);
    const float inv = 1.0f / sum;

    float* arow_out = attn + (long)(b * kO + o0 + wv) * kI;
    arow_out[ln]      = e0 * inv;
    arow_out[ln + 64] = e1 * inv;
}

} // namespace

extern "C" void kernel_launch(void* const* d_in, const int* in_sizes, int n_in,
                              void* d_out, int out_size, void* d_ws, size_t ws_size,
                              hipStream_t stream)
{
    const float* output  = (const float*)d_in[0];   // [B,O,D]
    const float* context = (const float*)d_in[1];   // [B,I,D]
    const int*   mask    = (const int*)d_in[2];     // [B,I]
    const float* w_out_w = (const float*)d_in[3];   // [D,D]
    const float* w_ctx_w = (const float*)d_in[4];   // [D,D]
    const float* w_b     = (const float*)d_in[5];   // [D]
    const float* score_w = (const float*)d_in[6];   // [D]
    const float* score_b = (const float*)d_in[7];   // scalar
    const float* lin_w   = (const float*)d_in[8];   // [2D,D]
    const float* lin_b   = (const float*)d_in[9];   // [D]

    float* out_main = (float*)d_out;                 // [B,O,D] final output
    float* out_attn = out_main + kOutAttnOff;        // [B,O,I] attn output
    // s_out overlays the final-output region (dead by the time step 5 writes it)
    float* s_out = out_main;
    float* s_ctx = (float*)d_ws;                     // 4 MB
    float* t_buf = s_ctx + (long)kB * kI * kD;       // 4 MB   (ws usage: 8 MB)

    const dim3 blk(256);

    // 1) s_out = output @ w_out_w + w_b   (w_b folded here)
    hipLaunchKernelGGL((gemm64<true, false>), dim3(16, 16, 1), blk, 0, stream,
        output, output, kD, kD, w_out_w, kD, w_b, s_out, kD, kD, 0L, 0L, 0L);
    // 2) s_ctx = context @ w_ctx_w
    hipLaunchKernelGGL((gemm64<false, false>), dim3(16, 16, 1), blk, 0, stream,
        context, context, kD, kD, w_ctx_w, kD, nullptr, s_ctx, kD, kD, 0L, 0L, 0L);
    // 3) attn = softmax(mask(leaky(s_out+s_ctx) . score_w + score_b))
    hipLaunchKernelGGL(score_softmax, dim3(8, 32, 1), blk, 0, stream,
        s_out, s_ctx, score_w, score_b, mask, out_attn);
    // 4) t = attn @ context (batched over b)
    hipLaunchKernelGGL((gemm64<false, false>), dim3(16, 2, 8), blk, 0, stream,
        out_attn, out_attn, kI, kI, context, kD, nullptr, t_buf, kD, kI,
        (long)kO * kI, (long)kI * kD, (long)kO * kD);
    // 5) out = leaky([t | output] @ lin_w + lin_b)
    hipLaunchKernelGGL((gemm64<true, true>), dim3(16, 16, 1), blk, 0, stream,
        t_buf, output, kD, kD, lin_w, kD, lin_b, out_main, kD, 2 * kD, 0L, 0L, 0L);
}

// Round 2
// 99.226 us; speedup vs baseline: 3.2044x; 3.2044x over previous
//
#include <hip/hip_runtime.h>

namespace {

constexpr int kB = 8, kO = 128, kI = 128, kD = 1024;
constexpr long kOutAttnOff = (long)kB * kO * kD;   // 1,048,576 floats

typedef __attribute__((ext_vector_type(8))) short short8;  // 8 bf16 = 4 VGPR
typedef __attribute__((ext_vector_type(4))) float f32x4;

__device__ __forceinline__ float leaky(float x) { return x > 0.0f ? x : 0.01f * x; }

// fp32 -> bf16, round-to-nearest-even (no NaN in this data)
__device__ __forceinline__ short f2bf(float f) {
    unsigned u = __builtin_bit_cast(unsigned, f);
    u += 0x7FFFu + ((u >> 16) & 1u);
    return (short)(u >> 16);
}

// ---------------------------------------------------------------------------
// Straight fp32->bf16 convert for `output` and `context` (1M elements each).
// 8 elems/thread, 262144 threads = 1024 blocks.
// ---------------------------------------------------------------------------
__global__ __launch_bounds__(256)
void conv_straight(const float* __restrict__ a, const float* __restrict__ b,
                   short* __restrict__ oa, short* __restrict__ ob)
{
    const int idx = blockIdx.x * 256 + threadIdx.x;
    const float* src; short* dst; int i;
    if (idx < (1 << 17)) { src = a; dst = oa; i = idx; }
    else                 { src = b; dst = ob; i = idx - (1 << 17); }
    const float4* s4 = (const float4*)src + (long)i * 2;
    const float4 v0 = s4[0], v1 = s4[1];
    short8 r;
    r[0] = f2bf(v0.x); r[1] = f2bf(v0.y); r[2] = f2bf(v0.z); r[3] = f2bf(v0.w);
    r[4] = f2bf(v1.x); r[5] = f2bf(v1.y); r[6] = f2bf(v1.z); r[7] = f2bf(v1.w);
    *(short8*)(dst + (long)i * 8) = r;
}

// ---------------------------------------------------------------------------
// Tiled transpose + fp32->bf16 convert: in fp32 [R][C] -> out bf16 [C][R].
// Segments: w_out_w (1024x1024), w_ctx_w (1024x1024), lin_w (2048x1024),
// context batched 8 x (128x1024). 64x64 tiles, 1280 blocks total.
// ---------------------------------------------------------------------------
__global__ __launch_bounds__(256)
void trans_conv(const float* __restrict__ w1, const float* __restrict__ w2,
                const float* __restrict__ lin, const float* __restrict__ ctx,
                short* __restrict__ w1t, short* __restrict__ w2t,
                short* __restrict__ lint, short* __restrict__ ctxt)
{
    __shared__ float T[64][68];   // 272B rows: 16B-aligned float4 stores
    const int bid = blockIdx.x;
    const float* src; short* dst; long C, R; int t2;
    if (bid < 256)       { src = w1;  dst = w1t;  R = 1024; C = 1024; t2 = bid; }
    else if (bid < 512)  { src = w2;  dst = w2t;  R = 1024; C = 1024; t2 = bid - 256; }
    else if (bid < 1024) { src = lin; dst = lint; R = 2048; C = 1024; t2 = bid - 512; }
    else {
        const int tt = bid - 1024; const int bz = tt >> 5; t2 = tt & 31;
        R = 128; C = 1024;
        src = ctx  + (long)bz * 128 * 1024;
        dst = ctxt + (long)bz * 1024 * 128;
    }
    const int tr = t2 >> 4, tc = t2 & 15;
    const int tid = threadIdx.x, r = tid >> 2, q = tid & 3;

    const float* s = src + (long)(tr * 64 + r) * C + tc * 64 + q * 16;
    const float4 a0 = ((const float4*)s)[0];
    const float4 a1 = ((const float4*)s)[1];
    const float4 a2 = ((const float4*)s)[2];
    const float4 a3 = ((const float4*)s)[3];
    *(float4*)&T[r][q * 16 + 0]  = a0;
    *(float4*)&T[r][q * 16 + 4]  = a1;
    *(float4*)&T[r][q * 16 + 8]  = a2;
    *(float4*)&T[r][q * 16 + 12] = a3;
    __syncthreads();

    short8 o0, o1;
#pragma unroll
    for (int j = 0; j < 8; ++j)  o0[j] = f2bf(T[q * 16 + j][r]);
#pragma unroll
    for (int j = 0; j < 8; ++j)  o1[j] = f2bf(T[q * 16 + 8 + j][r]);
    short* dp = dst + (long)(tc * 64 + r) * R + tr * 64 + q * 16;
    *(short8*)dp       = o0;
    *((short8*)dp + 1) = o1;
}

// ---------------------------------------------------------------------------
// bf16 MFMA GEMM: C = op(A @ B (+bias)).  A [M,K] bf16 row-major with dual
// source along K (k<ksplit -> A1, else A2, shared lda).  Bt = B^T bf16 [N][K]
// row-major (ldb). 64x64 tile, BK=64, 256 threads = 4 waves, wave = 32x32 via
// 2x2 of mfma_f32_16x16x32_bf16. LDS padded +8 shorts -> even bank spread.
// Batch strides sA/sB/sC (elements) by blockIdx.z.
// ---------------------------------------------------------------------------
template<bool BIAS, bool LEAKY, bool BF16OUT>
__global__ __launch_bounds__(256)
void gemm_mfma(const short* __restrict__ A1, const short* __restrict__ A2,
               int ksplit, int lda, const short* __restrict__ Bt, int ldb,
               const float* __restrict__ bias, void* __restrict__ Cout,
               int ldc, int K, long sA, long sB, long sC)
{
    __shared__ short As[64][72];
    __shared__ short Bs[64][72];
    const int tid = threadIdx.x;
    const int bn = blockIdx.x * 64, bm = blockIdx.y * 64;
    const long z = blockIdx.z;
    const short* A1z = A1 + z * sA;
    const short* A2z = A2 + z * sA;
    const short* Btz = Bt + z * sB;

    const int lane = tid & 63, w = tid >> 6;
    const int m0 = (w >> 1) * 32, n0 = (w & 1) * 32;
    const int fr = lane & 15, fg = (lane >> 4) * 8;
    const int sr = tid >> 2, sq = (tid & 3) * 16;   // staging: row, k-offset

    f32x4 acc00{}, acc01{}, acc10{}, acc11{};

    for (int k0 = 0; k0 < K; k0 += 64) {
        const int gk = k0 + sq;
        const short* asrc = (gk < ksplit)
            ? (A1z + (long)(bm + sr) * lda + gk)
            : (A2z + (long)(bm + sr) * lda + (gk - ksplit));
        const int4 av0 = ((const int4*)asrc)[0];
        const int4 av1 = ((const int4*)asrc)[1];
        const short* bsrc = Btz + (long)(bn + sr) * ldb + k0 + sq;
        const int4 bv0 = ((const int4*)bsrc)[0];
        const int4 bv1 = ((const int4*)bsrc)[1];
        __syncthreads();
        *(int4*)&As[sr][sq]     = av0;
        *(int4*)&As[sr][sq + 8] = av1;
        *(int4*)&Bs[sr][sq]     = bv0;
        *(int4*)&Bs[sr][sq + 8] = bv1;
        __syncthreads();
#pragma unroll
        for (int ks = 0; ks < 64; ks += 32) {
            const short8 a0 = *(const short8*)&As[m0 + fr][ks + fg];
            const short8 a1 = *(const short8*)&As[m0 + 16 + fr][ks + fg];
            const short8 b0 = *(const short8*)&Bs[n0 + fr][ks + fg];
            const short8 b1 = *(const short8*)&Bs[n0 + 16 + fr][ks + fg];
            acc00 = __builtin_amdgcn_mfma_f32_16x16x32_bf16(a0, b0, acc00, 0, 0, 0);
            acc01 = __builtin_amdgcn_mfma_f32_16x16x32_bf16(a0, b1, acc01, 0, 0, 0);
            acc10 = __builtin_amdgcn_mfma_f32_16x16x32_bf16(a1, b0, acc10, 0, 0, 0);
            acc11 = __builtin_amdgcn_mfma_f32_16x16x32_bf16(a1, b1, acc11, 0, 0, 0);
        }
    }

    float bv[2] = {0.0f, 0.0f};
    if (BIAS) {
        bv[0] = bias[bn + n0 + fr];
        bv[1] = bias[bn + n0 + 16 + fr];
    }
    float* Cf = (float*)Cout + z * sC;
    short* Ch = (short*)Cout + z * sC;
    const f32x4 accs[2][2] = {{acc00, acc01}, {acc10, acc11}};
#pragma unroll
    for (int mi = 0; mi < 2; ++mi)
#pragma unroll
        for (int ni = 0; ni < 2; ++ni)
#pragma unroll
            for (int r = 0; r < 4; ++r) {
                const int row = bm + m0 + mi * 16 + ((lane >> 4) << 2) + r;
                const int col = bn + n0 + ni * 16 + fr;
                float v = accs[mi][ni][r];
                if (BIAS)  v += bv[ni];
                if (LEAKY) v = leaky(v);
                if (BF16OUT) Ch[(long)row * ldc + col] = f2bf(v);
                else         Cf[(long)row * ldc + col] = v;
            }
}

// ---------------------------------------------------------------------------
// Fused score + mask + softmax (fp32 in, fp32 + bf16 attn out).
// Block: (b, o-pair). 4 waves: wave w -> o-row (w>>1), i-half (w&1); each
// thread handles ONE i. 512 blocks -> 2 blocks/CU. Cross-wave softmax via
// tiny LDS score buffer.
// ---------------------------------------------------------------------------
__global__ __launch_bounds__(256)
void score_softmax2(const float* __restrict__ s_out, const float* __restrict__ s_ctx,
                    const float* __restrict__ score_w, const float* __restrict__ score_b,
                    const int* __restrict__ mask, float* __restrict__ attn_f32,
                    short* __restrict__ attn_b16)
{
    __shared__ float As[2][1032];
    __shared__ float Cs[128][68];
    __shared__ float Wsh[1024];
    __shared__ float Ssc[2][128];
    __shared__ int   Msk[128];

    const int b   = blockIdx.x;
    const int o0  = blockIdx.y * 2;
    const int tid = threadIdx.x;
    const int wv  = tid >> 6;
    const int ln  = tid & 63;
    const int ow  = wv >> 1;          // o-row within pair (wave-uniform)
    const int ih  = wv & 1;           // i-half
    const int i   = ih * 64 + ln;     // this thread's i

    const float* arow = s_out + (long)(b * kO + o0) * kD;
#pragma unroll
    for (int q = 0; q < 2; ++q) {      // 512 float4
        const int t  = tid + q * 256;
        const int r  = t >> 8;
        const int c4 = (t & 255) * 4;
        *(float4*)&As[r][c4] = *(const float4*)&arow[(long)r * kD + c4];
    }
    *(float4*)&Wsh[tid * 4] = *(const float4*)&score_w[tid * 4];
    if (tid < 128) Msk[tid] = mask[b * kI + tid];

    float acc = 0.0f;
    const float* crow = s_ctx + (long)b * kI * kD;

    for (int dc = 0; dc < kD; dc += 64) {
        __syncthreads();
#pragma unroll
        for (int q = 0; q < 8; ++q) {  // 128x64 floats = 2048 float4
            const int t  = tid + q * 256;
            const int r  = t >> 4;
            const int c4 = (t & 15) * 4;
            *(float4*)&Cs[r][c4] = *(const float4*)&crow[(long)r * kD + dc + c4];
        }
        __syncthreads();
#pragma unroll
        for (int kk = 0; kk < 64; kk += 4) {
            const float4 w4 = *(const float4*)&Wsh[dc + kk];
            const float4 av = *(const float4*)&As[ow][dc + kk];   // broadcast
            const float4 c0 = *(const float4*)&Cs[i][kk];
            acc = fmaf(leaky(av.x + c0.x), w4.x, acc);
            acc = fmaf(leaky(av.y + c0.y), w4.y, acc);
            acc = fmaf(leaky(av.z + c0.z), w4.z, acc);
            acc = fmaf(leaky(av.w + c0.w), w4.w, acc);
        }
    }

    const float negInf = -__builtin_huge_valf();
    float s = acc + score_b[0];
    if (Msk[i] != 0) s = negInf;
    Ssc[ow][i] = s;
    __syncthreads();

    const float s0 = Ssc[ow][ln];
    const float s1 = Ssc[ow][ln + 64];
    float m = fmaxf(s0, s1);
#pragma unroll
    for (int d = 1; d < 64; d <<= 1) m = fmaxf(m, __shfl_xor(m, d, 64));
    const float e0 = __expf(s0 - m);
    const float e1 = __expf(s1 - m);
    float sum = e0 + e1;
#pragma unroll
    for (int d = 1; d < 64; d <<= 1) sum += __shfl_xor(sum, d, 64);
    const float inv = 1.0f / sum;

    if (ih == 0) {
        const long rowoff = (long)(b * kO + o0 + ow) * kI;
        float* ro = attn_f32 + rowoff;
        short* rh = attn_b16 + rowoff;
        const float p0 = e0 * inv, p1 = e1 * inv;
        ro[ln]      = p0;
        ro[ln + 64] = p1;
        rh[ln]      = f2bf(p0);
        rh[ln + 64] = f2bf(p1);
    }
}

} // namespace

extern "C" void kernel_launch(void* const* d_in, const int* in_sizes, int n_in,
                              void* d_out, int out_size, void* d_ws, size_t ws_size,
                              hipStream_t stream)
{
    const float* output  = (const float*)d_in[0];   // [B,O,D]
    const float* context = (const float*)d_in[1];   // [B,I,D]
    const int*   mask    = (const int*)d_in[2];     // [B,I]
    const float* w_out_w = (const float*)d_in[3];   // [D,D]
    const float* w_ctx_w = (const float*)d_in[4];   // [D,D]
    const float* w_b     = (const float*)d_in[5];   // [D]
    const float* score_w = (const float*)d_in[6];   // [D]
    const float* score_b = (const float*)d_in[7];   // scalar
    const float* lin_w   = (const float*)d_in[8];   // [2D,D]
    const float* lin_b   = (const float*)d_in[9];   // [D]

    float* out_main = (float*)d_out;                 // [B,O,D]
    float* out_attn = out_main + kOutAttnOff;        // [B,O,I]
    float* s_out    = out_main;                      // overlay: dead before step 5

    char* wp = (char*)d_ws;
    float* s_ctx = (float*)wp;  wp += (size_t)4 << 20;   // 4 MB fp32 [B*I][D]
    short* ob16  = (short*)wp;  wp += (size_t)2 << 20;   // output bf16
    short* cb16  = (short*)wp;  wp += (size_t)2 << 20;   // context bf16 (row-major)
    short* w1t   = (short*)wp;  wp += (size_t)2 << 20;   // w_out_w^T bf16 [N][K]
    short* w2t   = (short*)wp;  wp += (size_t)2 << 20;   // w_ctx_w^T bf16
    short* lint  = (short*)wp;  wp += (size_t)4 << 20;   // lin_w^T bf16 [1024][2048]
    short* ctxt  = (short*)wp;  wp += (size_t)2 << 20;   // context^T bf16, per-b [1024][128]
    short* attn16 = (short*)wp;                          // 256 KB bf16 attn
    short* t16 = (short*)s_ctx;                          // overlay: s_ctx dead after score

    const dim3 blk(256);

    // 0) conversions
    hipLaunchKernelGGL(conv_straight, dim3(1024), blk, 0, stream,
        output, context, ob16, cb16);
    hipLaunchKernelGGL(trans_conv, dim3(1280), blk, 0, stream,
        w_out_w, w_ctx_w, lin_w, context, w1t, w2t, lint, ctxt);

    // 1) s_out = output @ w_out_w + w_b   (fp32 C)
    hipLaunchKernelGGL((gemm_mfma<true, false, false>), dim3(16, 16, 1), blk, 0, stream,
        ob16, ob16, 1024, 1024, w1t, 1024, w_b, (void*)s_out, 1024, 1024, 0L, 0L, 0L);
    // 2) s_ctx = context @ w_ctx_w        (fp32 C)
    hipLaunchKernelGGL((gemm_mfma<false, false, false>), dim3(16, 16, 1), blk, 0, stream,
        cb16, cb16, 1024, 1024, w2t, 1024, nullptr, (void*)s_ctx, 1024, 1024, 0L, 0L, 0L);
    // 3) attn = softmax(mask(leaky(s_out + s_ctx + w_b) . score_w + score_b))
    hipLaunchKernelGGL(score_softmax2, dim3(8, 64, 1), blk, 0, stream,
        s_out, s_ctx, score_w, score_b, mask, out_attn, attn16);
    // 4) t = attn @ context  (batched, bf16 C into t16)
    hipLaunchKernelGGL((gemm_mfma<false, false, true>), dim3(16, 2, 8), blk, 0, stream,
        attn16, attn16, 128, 128, ctxt, 128, nullptr, (void*)t16, 1024, 128,
        (long)kO * kI, (long)kI * kD, (long)kO * kD);
    // 5) out = leaky([t | output] @ lin_w + lin_b)   (fp32 C)
    hipLaunchKernelGGL((gemm_mfma<true, true, false>), dim3(16, 16, 1), blk, 0, stream,
        t16, ob16, 1024, 1024, lint, 2048, lin_b, (void*)out_main, 1024, 2048, 0L, 0L, 0L);
}